// Round 3
// baseline (339.522 us; speedup 1.0000x reference)
//
#include <hip/hip_runtime.h>
#include <hip/hip_bf16.h>
#include <stdint.h>

typedef __bf16 bf16x8 __attribute__((ext_vector_type(8)));
typedef float floatx4 __attribute__((ext_vector_type(4)));

#define RR 147456   // 384*384 rows
#define NC 128      // channels
#define NN 384

union U32B { unsigned int u; __bf16 h[2]; };

__device__ inline floatx4 zero4() { floatx4 v; v[0]=0.f; v[1]=0.f; v[2]=0.f; v[3]=0.f; return v; }
__device__ inline float sigmoidf_(float x) { return 1.f / (1.f + __expf(-x)); }

// ---------------------------------------------------------------------------
// k0: transpose+cast the six fp32 128x128 weights into bf16 wt[slot][n*128+k]
// slots: 0=Wa 1=Wga 2=Wb 3=Wgb 4=Wg 5=Wo. Tiny; L2-resident.
// ---------------------------------------------------------------------------
__global__ __launch_bounds__(256) void k0_wt(
    const float* __restrict__ w0, const float* __restrict__ w1,
    const float* __restrict__ w2, const float* __restrict__ w3,
    const float* __restrict__ w4, const float* __restrict__ w5,
    __bf16* __restrict__ wt)
{
  const float* w;
  switch (blockIdx.x) {
    case 0: w = w0; break; case 1: w = w1; break; case 2: w = w2; break;
    case 3: w = w3; break; case 4: w = w4; break; default: w = w5; break;
  }
  __bf16* out = wt + blockIdx.x * 16384;
  const int t = threadIdx.x;
  for (int it = 0; it < 64; ++it) {
    int f = it * 256 + t;
    int n = f >> 7, k = f & 127;
    out[f] = (__bf16)w[k * 128 + n];   // wt[n][k] = W[k][n]
  }
}

// ---------------------------------------------------------------------------
// k2: per 64-row tile: LN1 fp32 (zn -> bf16 in LDS) -> 5 GEMMs (MFMA bf16)
//   a_t[c][row] = (zn@Wa+ba)*sig(zn@Wga+bga)   (channel-major, bf16)
//   b_t[c][row] = (zn@Wb+bb)*sig(zn@Wgb+bgb)
//   gate[row][c] = sig(zn@Wg+bg)               (natural layout, bf16)
// ---------------------------------------------------------------------------
__global__ __launch_bounds__(256) void k2_ln_gemm(
    const float* __restrict__ z, const float* __restrict__ ln1g, const float* __restrict__ ln1b,
    const __bf16* __restrict__ wt,
    const float* __restrict__ ba, const float* __restrict__ bga,
    const float* __restrict__ bb, const float* __restrict__ bgb,
    const float* __restrict__ bg,
    __bf16* __restrict__ at, __bf16* __restrict__ bt, __bf16* __restrict__ gate)
{
  __shared__ __align__(16) __bf16 zns[64][136];   // zn tile, padded stride
  __shared__ __align__(16) __bf16 wts[128][136];  // current W^T
  const int t = threadIdx.x;
  const int w = t >> 6, lane = t & 63;
  const int l15 = lane & 15, quad = lane >> 4;
  const int r0 = blockIdx.x * 64;

  // ---- LN1: wave w handles rows w*16..w*16+15, lane holds channels 2l,2l+1
  {
    float gg0 = ln1g[2*lane], gg1 = ln1g[2*lane+1];
    float bb0 = ln1b[2*lane], bb1 = ln1b[2*lane+1];
    for (int rr = 0; rr < 16; ++rr) {
      int row = w * 16 + rr;
      float2 xz = *(const float2*)(z + (size_t)(r0 + row) * NC + 2*lane);
      float x0 = xz.x, x1 = xz.y;
      float s = x0 + x1, q = x0*x0 + x1*x1;
      #pragma unroll
      for (int m = 1; m < 64; m <<= 1) { s += __shfl_xor(s, m); q += __shfl_xor(q, m); }
      float mean = s * (1.f/128.f);
      float var  = q * (1.f/128.f) - mean*mean;
      float rs = rsqrtf(var + 1e-5f);
      U32B uo;
      uo.h[0] = (__bf16)((x0 - mean) * rs * gg0 + bb0);
      uo.h[1] = (__bf16)((x1 - mean) * rs * gg1 + bb1);
      *(unsigned int*)&zns[row][2*lane] = uo.u;
    }
  }
  __syncthreads();

  auto stage = [&](const __bf16* wsrc) {   // wsrc is W^T rows [n][k], bf16
    #pragma unroll
    for (int it = 0; it < 8; ++it) {
      int f = (it * 256 + t) * 8;
      int n = f >> 7, k = f & 127;
      *(uint4*)&wts[n][k] = *(const uint4*)(wsrc + f);
    }
  };
  auto gemm = [&](floatx4* acc) {          // 64x128 tile; wave w owns 16 m-rows
    #pragma unroll
    for (int nt = 0; nt < 8; ++nt) acc[nt] = zero4();
    #pragma unroll
    for (int k0 = 0; k0 < 128; k0 += 32) {
      bf16x8 af = *(const bf16x8*)&zns[w*16 + l15][k0 + quad*8];
      #pragma unroll
      for (int nt = 0; nt < 8; ++nt) {
        bf16x8 bfr = *(const bf16x8*)&wts[nt*16 + l15][k0 + quad*8];
        acc[nt] = __builtin_amdgcn_mfma_f32_16x16x32_bf16(af, bfr, acc[nt], 0, 0, 0);
      }
    }
  };
  auto combine_store = [&](const floatx4* aP, const floatx4* aG,
                           const float* bia, const float* big, __bf16* dst) {
    #pragma unroll
    for (int nt = 0; nt < 8; ++nt) {
      int c = nt*16 + l15;
      float bav = bia[c], bgv = big[c];
      union { uint2 u2; __bf16 h[4]; } pk;
      #pragma unroll
      for (int r = 0; r < 4; ++r) {
        float p  = aP[nt][r] + bav;
        float gg = aG[nt][r] + bgv;
        pk.h[r] = (__bf16)(p * sigmoidf_(gg));
      }
      // 4 consecutive rows at fixed channel -> 8B store into channel-major plane
      *(uint2*)(dst + (size_t)c * RR + r0 + w*16 + quad*4) = pk.u2;
    }
  };

  floatx4 accP[8], accG[8];

  stage(wt + 0*16384); __syncthreads(); gemm(accP); __syncthreads();
  stage(wt + 1*16384); __syncthreads(); gemm(accG); __syncthreads();
  combine_store(accP, accG, ba, bga, at);
  stage(wt + 2*16384); __syncthreads(); gemm(accP); __syncthreads();
  stage(wt + 3*16384); __syncthreads(); gemm(accG); __syncthreads();
  combine_store(accP, accG, bb, bgb, bt);
  stage(wt + 4*16384); __syncthreads(); gemm(accG); __syncthreads();

  // gate: bounce through zns (dead after last gemm; each wave touches own rows)
  #pragma unroll
  for (int nt = 0; nt < 8; ++nt) {
    int c = nt*16 + l15;
    float bgv = bg[c];
    #pragma unroll
    for (int r = 0; r < 4; ++r)
      zns[w*16 + quad*4 + r][c] = (__bf16)sigmoidf_(accG[nt][r] + bgv);
  }
  __syncthreads();
  {
    // 64 rows x 128 ch; thread -> row t>>2, channels [(t&3)*32, +32)
    int row = t >> 2, c0 = (t & 3) * 32;
    uint4* dst = (uint4*)(gate + (size_t)(r0 + row) * NC + c0);
    const uint4* src = (const uint4*)&zns[row][c0];
    dst[0] = src[0]; dst[1] = src[1]; dst[2] = src[2]; dst[3] = src[3];
  }
}

// ---------------------------------------------------------------------------
// k3: triangle einsum. Per channel c: o_t[c] = A_c(384x384) @ B_c^T.
// grid (9 tiles, 128 channels); block computes 128x128 o-tile, wave = 64x64.
// ---------------------------------------------------------------------------
__global__ __launch_bounds__(256) void k3_tri(
    const __bf16* __restrict__ at, const __bf16* __restrict__ bt, float* __restrict__ o)
{
  __shared__ __align__(16) __bf16 As[128][72];
  __shared__ __align__(16) __bf16 Bs[128][72];
  const int t = threadIdx.x;
  const int w = t >> 6, lane = t & 63, l15 = lane & 15, quad = lane >> 4;
  const int c = blockIdx.y;
  const int i0 = (blockIdx.x / 3) * 128, j0 = (blockIdx.x % 3) * 128;
  const int wi = w >> 1, wj = w & 1;
  const size_t base = (size_t)c * RR;
  const __bf16* A  = at + base;
  const __bf16* Bp = bt + base;

  floatx4 acc[4][4];
  #pragma unroll
  for (int mt = 0; mt < 4; ++mt)
    #pragma unroll
    for (int nt = 0; nt < 4; ++nt) acc[mt][nt] = zero4();

  for (int kk = 0; kk < NN; kk += 64) {
    #pragma unroll
    for (int s2 = 0; s2 < 4; ++s2) {
      int f = s2 * 2048 + t * 8;        // contiguous across lanes
      int row = f >> 6, k = f & 63;
      *(uint4*)&As[row][k] = *(const uint4*)(A  + (size_t)(i0 + row) * NN + kk + k);
      *(uint4*)&Bs[row][k] = *(const uint4*)(Bp + (size_t)(j0 + row) * NN + kk + k);
    }
    __syncthreads();
    #pragma unroll
    for (int k0 = 0; k0 < 64; k0 += 32) {
      bf16x8 af[4], bfr[4];
      #pragma unroll
      for (int mt = 0; mt < 4; ++mt) af[mt]  = *(const bf16x8*)&As[wi*64 + mt*16 + l15][k0 + quad*8];
      #pragma unroll
      for (int nt = 0; nt < 4; ++nt) bfr[nt] = *(const bf16x8*)&Bs[wj*64 + nt*16 + l15][k0 + quad*8];
      #pragma unroll
      for (int mt = 0; mt < 4; ++mt)
        #pragma unroll
        for (int nt = 0; nt < 4; ++nt)
          acc[mt][nt] = __builtin_amdgcn_mfma_f32_16x16x32_bf16(af[mt], bfr[nt], acc[mt][nt], 0, 0, 0);
    }
    __syncthreads();
  }
  // store fp32, 64B-contiguous per (quad,reg) row
  #pragma unroll
  for (int mt = 0; mt < 4; ++mt) {
    #pragma unroll
    for (int r = 0; r < 4; ++r) {
      int i = i0 + wi*64 + mt*16 + quad*4 + r;
      float* orow = o + base + (size_t)i * NN + j0 + wj*64;
      #pragma unroll
      for (int nt = 0; nt < 4; ++nt) orow[nt*16 + l15] = acc[mt][nt][r];
    }
  }
}

// ---------------------------------------------------------------------------
// k4: per 64-position tile: gather o (channel-major fp32) -> LDS transpose ->
//     LN2 -> MFMA x Wo^T -> *gate -> fp32 out (direct store)
// ---------------------------------------------------------------------------
__global__ __launch_bounds__(256) void k4_out(
    const float* __restrict__ o, const __bf16* __restrict__ gate,
    const float* __restrict__ ln2g, const float* __restrict__ ln2b,
    const __bf16* __restrict__ wot, const float* __restrict__ bo,
    float* __restrict__ out)
{
  __shared__ __align__(16) float  osb[64][129];   // o tile [pos][c]
  __shared__ __align__(16) __bf16 ans[64][136];   // normalized tile (bf16)
  __shared__ __align__(16) __bf16 wts[128][136];  // Wo^T
  __shared__ __align__(16) __bf16 gbf[64][136];   // gate tile
  const int t = threadIdx.x;
  const int w = t >> 6, lane = t & 63, l15 = lane & 15, quad = lane >> 4;
  const int r0 = blockIdx.x * 64;

  // gather o: 16B-contiguous per channel plane, transpose into [pos][c]
  #pragma unroll
  for (int it = 0; it < 8; ++it) {
    int f = it * 1024 + t * 4;
    int cx = f >> 6, p = f & 63;
    float4 v = *(const float4*)(o + (size_t)cx * RR + r0 + p);
    osb[p+0][cx] = v.x; osb[p+1][cx] = v.y; osb[p+2][cx] = v.z; osb[p+3][cx] = v.w;
  }
  {
    int row = t >> 2, c0 = (t & 3) * 32;
    const uint4* src = (const uint4*)(gate + (size_t)(r0 + row) * NC + c0);
    uint4* dst = (uint4*)&gbf[row][c0];
    dst[0] = src[0]; dst[1] = src[1]; dst[2] = src[2]; dst[3] = src[3];
  }
  #pragma unroll
  for (int it = 0; it < 8; ++it) {
    int f = (it * 256 + t) * 8;
    int n = f >> 7, k = f & 127;
    *(uint4*)&wts[n][k] = *(const uint4*)(wot + f);
  }
  __syncthreads();

  // LN2 per position (fp32 stats)
  {
    float gg0 = ln2g[2*lane], gg1 = ln2g[2*lane+1];
    float bb0 = ln2b[2*lane], bb1 = ln2b[2*lane+1];
    for (int rr = 0; rr < 16; ++rr) {
      int row = w * 16 + rr;
      float x0 = osb[row][2*lane], x1 = osb[row][2*lane+1];
      float s = x0 + x1, q = x0*x0 + x1*x1;
      #pragma unroll
      for (int m = 1; m < 64; m <<= 1) { s += __shfl_xor(s, m); q += __shfl_xor(q, m); }
      float mean = s * (1.f/128.f);
      float var  = q * (1.f/128.f) - mean*mean;
      float rs = rsqrtf(var + 1e-5f);
      U32B uo;
      uo.h[0] = (__bf16)((x0 - mean) * rs * gg0 + bb0);
      uo.h[1] = (__bf16)((x1 - mean) * rs * gg1 + bb1);
      *(unsigned int*)&ans[row][2*lane] = uo.u;
    }
  }
  __syncthreads();

  floatx4 acc[8];
  #pragma unroll
  for (int nt = 0; nt < 8; ++nt) acc[nt] = zero4();
  #pragma unroll
  for (int k0 = 0; k0 < 128; k0 += 32) {
    bf16x8 af = *(const bf16x8*)&ans[w*16 + l15][k0 + quad*8];
    #pragma unroll
    for (int nt = 0; nt < 8; ++nt) {
      bf16x8 bfr = *(const bf16x8*)&wts[nt*16 + l15][k0 + quad*8];
      acc[nt] = __builtin_amdgcn_mfma_f32_16x16x32_bf16(af, bfr, acc[nt], 0, 0, 0);
    }
  }

  // epilogue: out = gate * (acc + bo), direct fp32 store (16-lane 64B runs)
  #pragma unroll
  for (int nt = 0; nt < 8; ++nt) {
    int c = nt*16 + l15;
    float bov = bo[c];
    #pragma unroll
    for (int r = 0; r < 4; ++r) {
      int rl = w*16 + quad*4 + r;
      out[(size_t)(r0 + rl) * NC + c] = (float)gbf[rl][c] * (acc[nt][r] + bov);
    }
  }
}

// ---------------------------------------------------------------------------
// Workspace layout (bytes):
//   a_t   @ 0          : 147456*128*2 = 37748736   (bf16, channel-major)
//   b_t   @ 37748736   : 37748736
//   gate  @ 75497472   : 37748736                  (bf16, natural layout)
//   o     @ 113246208  : 147456*128*4 = 75497472   (fp32, channel-major)
//   wt    @ 188743680  : 6*16384*2 = 196608        (transposed bf16 weights)
//   total 188940288
// ---------------------------------------------------------------------------
extern "C" void kernel_launch(void* const* d_in, const int* in_sizes, int n_in,
                              void* d_out, int out_size, void* d_ws, size_t ws_size,
                              hipStream_t stream) {
  const float* z    = (const float*)d_in[0];
  const float* l1g  = (const float*)d_in[1];
  const float* l1b  = (const float*)d_in[2];
  const float* l2g  = (const float*)d_in[3];
  const float* l2b  = (const float*)d_in[4];
  const float* Wa   = (const float*)d_in[5];
  const float* ba   = (const float*)d_in[6];
  const float* Wga  = (const float*)d_in[7];
  const float* bga  = (const float*)d_in[8];
  const float* Wb   = (const float*)d_in[9];
  const float* bb   = (const float*)d_in[10];
  const float* Wgb  = (const float*)d_in[11];
  const float* bgb  = (const float*)d_in[12];
  const float* Wg   = (const float*)d_in[13];
  const float* bg   = (const float*)d_in[14];
  const float* Wo   = (const float*)d_in[15];
  const float* bo   = (const float*)d_in[16];

  char* ws = (char*)d_ws;
  __bf16* at_  = (__bf16*)(ws + 0);
  __bf16* bt_  = (__bf16*)(ws + 37748736);
  __bf16* gate = (__bf16*)(ws + 75497472);
  float*  o    = (float*) (ws + 113246208);
  __bf16* wt   = (__bf16*)(ws + 188743680);

  hipLaunchKernelGGL(k0_wt, dim3(6), dim3(256), 0, stream, Wa, Wga, Wb, Wgb, Wg, Wo, wt);
  hipLaunchKernelGGL(k2_ln_gemm, dim3(2304), dim3(256), 0, stream,
                     z, l1g, l1b, wt, ba, bga, bb, bgb, bg, at_, bt_, gate);
  hipLaunchKernelGGL(k3_tri, dim3(9, 128), dim3(256), 0, stream, at_, bt_, o);
  hipLaunchKernelGGL(k4_out, dim3(2304), dim3(256), 0, stream,
                     o, gate, l2g, l2b, wt + 5*16384, bo, (float*)d_out);
}